// Round 5
// baseline (196.717 us; speedup 1.0000x reference)
//
#include <hip/hip_runtime.h>
#include <hip/hip_fp16.h>

// RoIAlignRotated on MI355X — R4.
// vs R2 (best): (a) each roi split across 2 blocks (bins 0-24 / 25-48) and
// fp16 output staging -> LDS 56.8 KB -> 19.2 KB -> 8 blocks/CU (R2 was
// latency-starved at 2 blocks/CU); (b) AoS float4/int4 sample table (b128
// broadcasts) + byte-offset indices to cut per-corner VALU; (c) transpose
// does 8 y-rows per block (fixed-cost amortization; it was block-overhead
// bound at 52us regardless of vectorization).

#define B_ 2
#define C_ 256
#define H_ 200
#define W_ 200
#define OUTHW 7
#define GRID_S 14          // OUTHW * sampling_ratio(2)
#define NSAMP 196          // 14*14
#define ELEMS (C_ * OUTHW * OUTHW)  // 12544

// ---------- NCHW f32 -> NHWC fp16, LDS-tiled, 8 y-rows per block ----------
__global__ __launch_bounds__(256) void transpose_h_kernel(
    const float* __restrict__ feat, __half* __restrict__ featT)
{
    __shared__ float tile[64][65];   // stride 65: <=2-way on both phases
    const int x0 = blockIdx.x * 64;
    const int c0 = blockIdx.y * 64;
    const int zz = blockIdx.z;       // b*25 + y8
    const int b  = zz / 25;
    const int y0 = (zz - b * 25) * 8;
    const int t  = threadIdx.x;
    const int nx = min(64, W_ - x0);

    const int rr = t >> 4;           // read: channel sub-row
    const int jj = t & 15;           // read: float4 index along x
    const int ii = t >> 4;           // write: x sub-index
    const int cq = (t & 15) * 4;     // write: channel quad

    for (int dy = 0; dy < 8; ++dy) {
        const int y = y0 + dy;
        if (jj * 4 < nx) {
            #pragma unroll
            for (int p = 0; p < 4; ++p) {
                const int cl = p * 16 + rr;
                const float4 v = *(const float4*)(feat +
                    ((size_t)(b * C_ + c0 + cl) * H_ + y) * W_ + x0 + jj * 4);
                *(float4*)&tile[cl][jj * 4] = v;
            }
        }
        __syncthreads();
        #pragma unroll
        for (int p = 0; p < 4; ++p) {
            const int i = p * 16 + ii;
            if (i < nx) {
                union { __half2 h2[2]; float2 f2; } u;
                u.h2[0] = __floats2half2_rn(tile[cq + 0][i], tile[cq + 1][i]);
                u.h2[1] = __floats2half2_rn(tile[cq + 2][i], tile[cq + 3][i]);
                *(float2*)(featT +
                    ((size_t)(b * H_ + y) * W_ + x0 + i) * C_ + c0 + cq) = u.f2;
            }
        }
        __syncthreads();
    }
}

// ---------- per-roi sample table (channel-independent), AoS ----------
// byte_mode: idx components are BYTE offsets into fp16 NHWC (pix*C_*2);
// else element offsets into one f32 NCHW channel plane (pix), batch via s_b.
__device__ __forceinline__ void build_table(
    const float* __restrict__ rois, int n, int t,
    float4* s_w4, int4* s_idx4, int byte_mode, int* s_b)
{
    const float spatial_scale = 0.25f;
    if (t == 0 && s_b) *s_b = (int)rois[n * 6 + 0];
    if (t < NSAMP) {
        const int   b  = (int)rois[n * 6 + 0];
        const float cx = rois[n * 6 + 1] * spatial_scale;
        const float cy = rois[n * 6 + 2] * spatial_scale;
        const float rw = fmaxf(rois[n * 6 + 3] * spatial_scale, 1.0f);
        const float rh = fmaxf(rois[n * 6 + 4] * spatial_scale, 1.0f);
        const float th = rois[n * 6 + 5];
        const float cosv = cosf(th), sinv = sinf(th);

        const float bin_h = rh * (1.0f / OUTHW);
        const float bin_w = rw * (1.0f / OUTHW);
        const int row = t / GRID_S;
        const int col = t % GRID_S;

        const float yy = -rh * 0.5f + ((float)row + 0.5f) * 0.5f * bin_h;
        const float xx = -rw * 0.5f + ((float)col + 0.5f) * 0.5f * bin_w;

        const float y = yy * cosv - xx * sinv + cy;
        const float x = yy * sinv + xx * cosv + cx;

        const bool inside = (y >= -1.0f) && (y <= (float)H_) &&
                            (x >= -1.0f) && (x <= (float)W_);

        const float yc = fmaxf(y, 0.0f);
        const float xc = fmaxf(x, 0.0f);
        const float fy = floorf(yc);
        const float fx = floorf(xc);
        int yl = min((int)fy, H_ - 1);
        int xl = min((int)fx, W_ - 1);
        const int yh = min(yl + 1, H_ - 1);
        const int xh = min(xl + 1, W_ - 1);
        const float ly = (fy >= (float)(H_ - 1)) ? 0.0f : (yc - fy);
        const float lx = (fx >= (float)(W_ - 1)) ? 0.0f : (xc - fx);
        const float hy = 1.0f - ly;
        const float hx = 1.0f - lx;

        const float m = inside ? 0.25f : 0.0f;   // fold inside-mask + 2x2 mean
        s_w4[t] = make_float4(hy * hx * m, hy * lx * m, ly * hx * m, ly * lx * m);

        const int bb = byte_mode ? b : 0;
        const int scale = byte_mode ? (C_ * 2) : 1;
        s_idx4[t] = make_int4(((bb * H_ + yl) * W_ + xl) * scale,
                              ((bb * H_ + yl) * W_ + xh) * scale,
                              ((bb * H_ + yh) * W_ + xl) * scale,
                              ((bb * H_ + yh) * W_ + xh) * scale);
    }
}

// ---------- main kernel: 2 blocks per roi, fp16 staging ----------
template <int BC>
__device__ __forceinline__ void drain(
    const __half s_out[25][258], float* __restrict__ ob, int B0, int t)
{
    #pragma unroll
    for (int k = 0; k < BC; ++k) {
        const int m = t + k * 256;
        const int c = m / BC;               // compile-time BC -> magic mul
        const int j = m - c * BC;
        ob[c * 49 + B0 + j] =
            __half2float(s_out[j][(c & 3) * 64 + (c >> 2)]);
    }
}

__global__ __launch_bounds__(256) void roi_main_split(
    const __half* __restrict__ featT,
    const float* __restrict__ rois,
    float* __restrict__ out)
{
    __shared__ float4 s_w4[NSAMP];      // 3136 B
    __shared__ int4   s_idx4[NSAMP];    // 3136 B (byte offsets)
    __shared__ __half s_out[25][258];   // 12900 B; total ~19.2 KB -> 8 blk/CU

    const int n    = blockIdx.x >> 1;
    const int half = blockIdx.x & 1;
    const int B0   = half * 25;
    const int BC_r = half ? 24 : 25;
    const int t    = threadIdx.x;

    build_table(rois, n, t, s_w4, s_idx4, 1, nullptr);
    __syncthreads();

    const int lane = t & 63;
    const int wave = t >> 6;
    const char* __restrict__ fbase = (const char*)featT + lane * 8; // 4 ch/lane

    for (int bin = B0 + wave; bin < B0 + BC_r; bin += 4) {
        const int oy = bin / OUTHW;
        const int ox = bin - oy * OUTHW;
        float a0 = 0.f, a1 = 0.f, a2 = 0.f, a3 = 0.f;
        #pragma unroll
        for (int j = 0; j < 2; ++j) {
            #pragma unroll
            for (int i = 0; i < 2; ++i) {
                const int s = (oy * 2 + j) * GRID_S + (ox * 2 + i);
                const float4 w = s_w4[s];       // one b128 broadcast
                const int4   ix = s_idx4[s];    // one b128 broadcast
                const float* wq = (const float*)&w;
                const int*   iq = (const int*)&ix;
                #pragma unroll
                for (int q = 0; q < 4; ++q) {
                    const float2 rv =
                        *(const float2*)(fbase + (unsigned)iq[q]);
                    const __half2* hp = (const __half2*)&rv;
                    const float2 fa = __half22float2(hp[0]);
                    const float2 fb = __half22float2(hp[1]);
                    a0 = fmaf(wq[q], fa.x, a0);
                    a1 = fmaf(wq[q], fa.y, a1);
                    a2 = fmaf(wq[q], fb.x, a2);
                    a3 = fmaf(wq[q], fb.y, a3);
                }
            }
        }
        const int jb = bin - B0;
        s_out[jb][0 * 64 + lane] = __float2half(a0);  // swizzle: c -> (c&3)*64+(c>>2)
        s_out[jb][1 * 64 + lane] = __float2half(a1);
        s_out[jb][2 * 64 + lane] = __float2half(a2);
        s_out[jb][3 * 64 + lane] = __float2half(a3);
    }
    __syncthreads();

    float* __restrict__ ob = out + (size_t)n * ELEMS;
    if (half == 0) drain<25>(s_out, ob, 0, t);
    else           drain<24>(s_out, ob, 25, t);
}

// ---------- fallback (known-correct NCHW path, no workspace) ----------
__global__ __launch_bounds__(256) void roi_main_nchw(
    const float* __restrict__ feat,
    const float* __restrict__ rois,
    float* __restrict__ out)
{
    const int n = blockIdx.x;
    const int t = threadIdx.x;
    __shared__ float4 s_w4[NSAMP];
    __shared__ int4   s_idx4[NSAMP];
    __shared__ int    s_b;

    build_table(rois, n, t, s_w4, s_idx4, 0, &s_b);
    __syncthreads();

    const float* __restrict__ fb = feat + (size_t)s_b * (size_t)(C_ * H_ * W_);
    float* __restrict__ ob = out + (size_t)n * (size_t)ELEMS;

    for (int e = t; e < ELEMS; e += 256) {
        const int c   = e / 49;
        const int bin = e - c * 49;
        const int oy  = bin / 7;
        const int ox  = bin - oy * 7;
        const float* __restrict__ fc = fb + c * (H_ * W_);
        float acc = 0.0f;
        #pragma unroll
        for (int j = 0; j < 2; ++j) {
            #pragma unroll
            for (int i = 0; i < 2; ++i) {
                const int s = (oy * 2 + j) * GRID_S + (ox * 2 + i);
                const float4 w = s_w4[s];
                const int4   ix = s_idx4[s];
                acc += w.x * fc[ix.x];
                acc += w.y * fc[ix.y];
                acc += w.z * fc[ix.z];
                acc += w.w * fc[ix.w];
            }
        }
        ob[e] = acc;
    }
}

extern "C" void kernel_launch(void* const* d_in, const int* in_sizes, int n_in,
                              void* d_out, int out_size, void* d_ws, size_t ws_size,
                              hipStream_t stream) {
    const float* feat = (const float*)d_in[0];
    const float* rois = (const float*)d_in[1];
    float* out = (float*)d_out;
    const int N = in_sizes[1] / 6;  // 1000

    const size_t need = (size_t)B_ * H_ * W_ * C_ * sizeof(__half); // 41 MB
    if (ws_size >= need) {
        __half* featT = (__half*)d_ws;
        dim3 tg((W_ + 63) / 64, C_ / 64, B_ * 25);  // 8 y-rows per block
        transpose_h_kernel<<<tg, 256, 0, stream>>>(feat, featT);
        roi_main_split<<<2 * N, 256, 0, stream>>>(featT, rois, out);
    } else {
        roi_main_nchw<<<N, 256, 0, stream>>>(feat, rois, out);
    }
}

// Round 6
// 188.794 us; speedup vs baseline: 1.0420x; 1.0420x over previous
//
#include <hip/hip_runtime.h>
#include <hip/hip_fp16.h>

// RoIAlignRotated on MI355X — R5.
// vs R4: rocprof showed occupancy 28->49% with zero speedup and FETCH=142 MB
// for a 41 MB featT -> L2-fill bound, not wave-starved. This round attacks
// locality only (kernel bodies unchanged from R4):
//  (a) tiny bitonic sort (fused as one extra block of the transpose grid)
//      orders rois by (batch, morton16(cy,cx)) -> perm in d_ws;
//  (b) main grid swizzle h=(b&7)*250+(b>>3): each XCD (xcd≈blockIdx%8) gets a
//      contiguous spatial cluster, and both halves of a roi share an XCD ->
//      gather lines fetched into one L2 instead of two, drain lines merge.

#define B_ 2
#define C_ 256
#define H_ 200
#define W_ 200
#define OUTHW 7
#define GRID_S 14          // OUTHW * sampling_ratio(2)
#define NSAMP 196          // 14*14
#define ELEMS (C_ * OUTHW * OUTHW)  // 12544
#define FEATT_BYTES ((size_t)B_ * H_ * W_ * C_ * sizeof(__half))  // 40.96 MB

// ---------- NCHW f32 -> NHWC fp16 transpose + fused roi sort ----------
__global__ __launch_bounds__(256) void transpose_sort_kernel(
    const float* __restrict__ feat, __half* __restrict__ featT,
    const float* __restrict__ rois, int* __restrict__ perm, int nroi)
{
    const int t = threadIdx.x;

    if (blockIdx.z == B_ * 25) {
        // ---- sort block (runs concurrent with transpose blocks) ----
        if (blockIdx.x != 0 || blockIdx.y != 0) return;
        __shared__ unsigned spack[1024];   // key<<10 | idx
        for (int i = t; i < 1024; i += 256) {
            unsigned pk = 0xFFFFFFFFu;
            if (i < nroi) {
                const int b  = (int)rois[i * 6 + 0];
                const int cx = (int)(rois[i * 6 + 1] * 0.25f);
                const int cy = (int)(rois[i * 6 + 2] * 0.25f);
                const int tx = min(15, max(0, cx >> 4));
                const int ty = min(15, max(0, cy >> 4));
                unsigned m = 0;
                #pragma unroll
                for (int k = 0; k < 4; ++k)
                    m |= (((unsigned)(ty >> k) & 1u) << (2 * k + 1)) |
                         (((unsigned)(tx >> k) & 1u) << (2 * k));
                pk = ((((unsigned)b << 8) | m) << 10) | (unsigned)i;
            }
            spack[i] = pk;
        }
        __syncthreads();
        for (unsigned k = 2; k <= 1024; k <<= 1) {
            for (unsigned j = k >> 1; j > 0; j >>= 1) {
                for (unsigned i = t; i < 1024; i += 256) {
                    const unsigned ixj = i ^ j;
                    if (ixj > i) {
                        const unsigned a = spack[i], c = spack[ixj];
                        const bool asc = ((i & k) == 0);
                        if (asc ? (a > c) : (a < c)) {
                            spack[i] = c; spack[ixj] = a;
                        }
                    }
                }
                __syncthreads();
            }
        }
        for (int i = t; i < nroi; i += 256)
            perm[i] = (int)(spack[i] & 1023u);
        return;
    }

    // ---- transpose body (identical structure to R4) ----
    __shared__ float tile[64][65];
    const int x0 = blockIdx.x * 64;
    const int c0 = blockIdx.y * 64;
    const int zz = blockIdx.z;       // b*25 + y8
    const int b  = zz / 25;
    const int y0 = (zz - b * 25) * 8;
    const int nx = min(64, W_ - x0);

    const int rr = t >> 4;           // read: channel sub-row
    const int jj = t & 15;           // read: float4 index along x
    const int ii = t >> 4;           // write: x sub-index
    const int cq = (t & 15) * 4;     // write: channel quad

    for (int dy = 0; dy < 8; ++dy) {
        const int y = y0 + dy;
        if (jj * 4 < nx) {
            #pragma unroll
            for (int p = 0; p < 4; ++p) {
                const int cl = p * 16 + rr;
                const float4 v = *(const float4*)(feat +
                    ((size_t)(b * C_ + c0 + cl) * H_ + y) * W_ + x0 + jj * 4);
                *(float4*)&tile[cl][jj * 4] = v;
            }
        }
        __syncthreads();
        #pragma unroll
        for (int p = 0; p < 4; ++p) {
            const int i = p * 16 + ii;
            if (i < nx) {
                union { __half2 h2[2]; float2 f2; } u;
                u.h2[0] = __floats2half2_rn(tile[cq + 0][i], tile[cq + 1][i]);
                u.h2[1] = __floats2half2_rn(tile[cq + 2][i], tile[cq + 3][i]);
                *(float2*)(featT +
                    ((size_t)(b * H_ + y) * W_ + x0 + i) * C_ + c0 + cq) = u.f2;
            }
        }
        __syncthreads();
    }
}

// ---------- per-roi sample table (channel-independent), AoS ----------
__device__ __forceinline__ void build_table(
    const float* __restrict__ rois, int n, int t,
    float4* s_w4, int4* s_idx4, int byte_mode, int* s_b)
{
    const float spatial_scale = 0.25f;
    if (t == 0 && s_b) *s_b = (int)rois[n * 6 + 0];
    if (t < NSAMP) {
        const int   b  = (int)rois[n * 6 + 0];
        const float cx = rois[n * 6 + 1] * spatial_scale;
        const float cy = rois[n * 6 + 2] * spatial_scale;
        const float rw = fmaxf(rois[n * 6 + 3] * spatial_scale, 1.0f);
        const float rh = fmaxf(rois[n * 6 + 4] * spatial_scale, 1.0f);
        const float th = rois[n * 6 + 5];
        const float cosv = cosf(th), sinv = sinf(th);

        const float bin_h = rh * (1.0f / OUTHW);
        const float bin_w = rw * (1.0f / OUTHW);
        const int row = t / GRID_S;
        const int col = t % GRID_S;

        const float yy = -rh * 0.5f + ((float)row + 0.5f) * 0.5f * bin_h;
        const float xx = -rw * 0.5f + ((float)col + 0.5f) * 0.5f * bin_w;

        const float y = yy * cosv - xx * sinv + cy;
        const float x = yy * sinv + xx * cosv + cx;

        const bool inside = (y >= -1.0f) && (y <= (float)H_) &&
                            (x >= -1.0f) && (x <= (float)W_);

        const float yc = fmaxf(y, 0.0f);
        const float xc = fmaxf(x, 0.0f);
        const float fy = floorf(yc);
        const float fx = floorf(xc);
        int yl = min((int)fy, H_ - 1);
        int xl = min((int)fx, W_ - 1);
        const int yh = min(yl + 1, H_ - 1);
        const int xh = min(xl + 1, W_ - 1);
        const float ly = (fy >= (float)(H_ - 1)) ? 0.0f : (yc - fy);
        const float lx = (fx >= (float)(W_ - 1)) ? 0.0f : (xc - fx);
        const float hy = 1.0f - ly;
        const float hx = 1.0f - lx;

        const float m = inside ? 0.25f : 0.0f;   // fold inside-mask + 2x2 mean
        s_w4[t] = make_float4(hy * hx * m, hy * lx * m, ly * hx * m, ly * lx * m);

        const int bb = byte_mode ? b : 0;
        const int scale = byte_mode ? (C_ * 2) : 1;
        s_idx4[t] = make_int4(((bb * H_ + yl) * W_ + xl) * scale,
                              ((bb * H_ + yl) * W_ + xh) * scale,
                              ((bb * H_ + yh) * W_ + xl) * scale,
                              ((bb * H_ + yh) * W_ + xh) * scale);
    }
}

// ---------- main kernel: 2 blocks per roi, XCD-aware sorted mapping ----------
template <int BC>
__device__ __forceinline__ void drain(
    const __half s_out[25][258], float* __restrict__ ob, int B0, int t)
{
    #pragma unroll
    for (int k = 0; k < BC; ++k) {
        const int m = t + k * 256;
        const int c = m / BC;
        const int j = m - c * BC;
        ob[c * 49 + B0 + j] =
            __half2float(s_out[j][(c & 3) * 64 + (c >> 2)]);
    }
}

__global__ __launch_bounds__(256) void roi_main_split(
    const __half* __restrict__ featT,
    const float* __restrict__ rois,
    const int* __restrict__ perm,
    float* __restrict__ out,
    int slots)   // = 2N/8; h=(b&7)*slots+(b>>3): cluster per XCD, halves co-XCD
{
    __shared__ float4 s_w4[NSAMP];      // 3136 B
    __shared__ int4   s_idx4[NSAMP];    // 3136 B (byte offsets)
    __shared__ __half s_out[25][258];   // 12900 B; total ~19.2 KB -> 8 blk/CU

    const int h    = (blockIdx.x & 7) * slots + (blockIdx.x >> 3);
    const int n    = perm[h >> 1];
    const int half = h & 1;
    const int B0   = half * 25;
    const int BC_r = half ? 24 : 25;
    const int t    = threadIdx.x;

    build_table(rois, n, t, s_w4, s_idx4, 1, nullptr);
    __syncthreads();

    const int lane = t & 63;
    const int wave = t >> 6;
    const char* __restrict__ fbase = (const char*)featT + lane * 8; // 4 ch/lane

    for (int bin = B0 + wave; bin < B0 + BC_r; bin += 4) {
        const int oy = bin / OUTHW;
        const int ox = bin - oy * OUTHW;
        float a0 = 0.f, a1 = 0.f, a2 = 0.f, a3 = 0.f;
        #pragma unroll
        for (int j = 0; j < 2; ++j) {
            #pragma unroll
            for (int i = 0; i < 2; ++i) {
                const int s = (oy * 2 + j) * GRID_S + (ox * 2 + i);
                const float4 w = s_w4[s];       // one b128 broadcast
                const int4   ix = s_idx4[s];    // one b128 broadcast
                const float* wq = (const float*)&w;
                const int*   iq = (const int*)&ix;
                #pragma unroll
                for (int q = 0; q < 4; ++q) {
                    const float2 rv =
                        *(const float2*)(fbase + (unsigned)iq[q]);
                    const __half2* hp = (const __half2*)&rv;
                    const float2 fa = __half22float2(hp[0]);
                    const float2 fb = __half22float2(hp[1]);
                    a0 = fmaf(wq[q], fa.x, a0);
                    a1 = fmaf(wq[q], fa.y, a1);
                    a2 = fmaf(wq[q], fb.x, a2);
                    a3 = fmaf(wq[q], fb.y, a3);
                }
            }
        }
        const int jb = bin - B0;
        s_out[jb][0 * 64 + lane] = __float2half(a0);  // c -> col (c&3)*64+(c>>2)
        s_out[jb][1 * 64 + lane] = __float2half(a1);
        s_out[jb][2 * 64 + lane] = __float2half(a2);
        s_out[jb][3 * 64 + lane] = __float2half(a3);
    }
    __syncthreads();

    float* __restrict__ ob = out + (size_t)n * ELEMS;
    if (half == 0) drain<25>(s_out, ob, 0, t);
    else           drain<24>(s_out, ob, 25, t);
}

// ---------- fallback (known-correct NCHW path, no workspace) ----------
__global__ __launch_bounds__(256) void roi_main_nchw(
    const float* __restrict__ feat,
    const float* __restrict__ rois,
    float* __restrict__ out)
{
    const int n = blockIdx.x;
    const int t = threadIdx.x;
    __shared__ float4 s_w4[NSAMP];
    __shared__ int4   s_idx4[NSAMP];
    __shared__ int    s_b;

    build_table(rois, n, t, s_w4, s_idx4, 0, &s_b);
    __syncthreads();

    const float* __restrict__ fb = feat + (size_t)s_b * (size_t)(C_ * H_ * W_);
    float* __restrict__ ob = out + (size_t)n * (size_t)ELEMS;

    for (int e = t; e < ELEMS; e += 256) {
        const int c   = e / 49;
        const int bin = e - c * 49;
        const int oy  = bin / 7;
        const int ox  = bin - oy * 7;
        const float* __restrict__ fc = fb + c * (H_ * W_);
        float acc = 0.0f;
        #pragma unroll
        for (int j = 0; j < 2; ++j) {
            #pragma unroll
            for (int i = 0; i < 2; ++i) {
                const int s = (oy * 2 + j) * GRID_S + (ox * 2 + i);
                const float4 w = s_w4[s];
                const int4   ix = s_idx4[s];
                acc += w.x * fc[ix.x];
                acc += w.y * fc[ix.y];
                acc += w.z * fc[ix.z];
                acc += w.w * fc[ix.w];
            }
        }
        ob[e] = acc;
    }
}

extern "C" void kernel_launch(void* const* d_in, const int* in_sizes, int n_in,
                              void* d_out, int out_size, void* d_ws, size_t ws_size,
                              hipStream_t stream) {
    const float* feat = (const float*)d_in[0];
    const float* rois = (const float*)d_in[1];
    float* out = (float*)d_out;
    const int N = in_sizes[1] / 6;  // 1000

    const bool can = (ws_size >= FEATT_BYTES + 4096) &&
                     (N >= 1) && (N <= 1024) && ((2 * N) % 8 == 0);
    if (can) {
        __half* featT = (__half*)d_ws;
        int* perm = (int*)((char*)d_ws + FEATT_BYTES);
        dim3 tg((W_ + 63) / 64, C_ / 64, B_ * 25 + 1);  // +1 z-slice = sort block
        transpose_sort_kernel<<<tg, 256, 0, stream>>>(feat, featT, rois, perm, N);
        roi_main_split<<<2 * N, 256, 0, stream>>>(featT, rois, perm, out,
                                                  (2 * N) / 8);
    } else {
        roi_main_nchw<<<N, 256, 0, stream>>>(feat, rois, out);
    }
}